// Round 5
// baseline (814.487 us; speedup 1.0000x reference)
//
#include <hip/hip_runtime.h>
#include <math.h>

#define N_    128
#define CIN   64
#define COUT  128
#define CINT  32
#define S_    3
#define T_    64
#define V_    25
#define EPSF  1e-5f
#define LN1E4 9.210340371976184f
#define P_    (N_*T_*V_)   // 204800 positions

typedef __attribute__((ext_vector_type(8))) short bf16x8;
typedef __attribute__((ext_vector_type(4))) unsigned short bf16x4;
typedef __attribute__((ext_vector_type(4))) float f32x4;

#define MFMA(a,b,c) __builtin_amdgcn_mfma_f32_16x16x32_bf16(a,b,c,0,0,0)

// ---- workspace byte offsets (round-3 verified map) ---------------------------
#define OFF_WQS    0u          // 192x64 bf16           -> 24576
#define OFF_WQT    24576u      // 192x128               -> 73728
#define OFF_WOUTS  73728u      // 128x192 prescaled     -> 122880
#define OFF_WDS1   122880u     // 128x64                -> 139264
#define OFF_WFFS   139264u     // 128x128               -> 172032
#define OFF_WDS2   172032u     // 128x64                -> 188416
#define OFF_WOUTT  188416u     // 128x384               -> 286720
#define OFF_WDT1   286720u     // 128x128               -> 319488
#define OFF_WFFT   319488u     // 128x128               -> 352256
#define OFF_WDT2   352256u     // 128x128               -> 385024
#define OFF_SHS    385024u     // fp32 192x32           -> 409600
#define OFF_SHT    409600u     // fp32 192x64           -> 458752
#define OFF_SHA    458752u
#define OFF_SHB    459264u
#define OFF_SHC    459776u
#define OFF_SHD    460288u     //                       -> 460800
#define OFF_ATTST  460800u     // [n][s][32v][32u] bf16 -> 1247232
#define OFF_ATTTT  1247232u    // [n][s][64q][64t] bf16 -> 4392960
#define OFF_XCL    4392960u    // [pos][64]  bf16       -> 30607360
#define OFF_YCL    30607360u   // [pos][128] bf16 (y)   -> 83036160
#define OFF_RB     83036160u   // [pos][128] bf16 (y1 then z1) -> 135464960
#define OFF_RA     135464960u  // [pos][192] bf16 (qk_s -> ys -> qk_t) -> 214108160

__device__ __forceinline__ unsigned short f2bf(float f) {
  union { float f; unsigned int u; } v; v.f = f;
  unsigned int u = v.u;
  return (unsigned short)((u + 0x7FFFu + ((u >> 16) & 1u)) >> 16);
}
__device__ __forceinline__ float bnscale(const float* bn, int o) {
  return bn[o] * rsqrtf(bn[3*COUT + o] + EPSF);
}
__device__ __forceinline__ float bnshift(const float* bn, const float* b, int o) {
  return (b[o] - bn[2*COUT + o]) * bnscale(bn, o) + bn[COUT + o];
}
__device__ __forceinline__ float pe_val(int c, int p, float inv) {
  float freq = expf(-(float)(c >> 1) * inv);
  float arg = (float)p * freq;
  return (c & 1) ? cosf(arg) : sinf(arg);
}

// =============================================================================
// prep (round-3 verified): bf16 BN-prescaled weights, PE-folded shift tables
// =============================================================================
__global__ __launch_bounds__(256) void k_prep(
    const float* __restrict__ wqks, const float* __restrict__ bqks,
    const float* __restrict__ wouts, const float* __restrict__ bouts, const float* __restrict__ bnouts,
    const float* __restrict__ wffs, const float* __restrict__ bffs, const float* __restrict__ bnffs,
    const float* __restrict__ wds1, const float* __restrict__ bds1, const float* __restrict__ bnds1,
    const float* __restrict__ wds2, const float* __restrict__ bds2, const float* __restrict__ bnds2,
    const float* __restrict__ wqkt, const float* __restrict__ bqkt,
    const float* __restrict__ woutt, const float* __restrict__ boutt, const float* __restrict__ bnoutt,
    const float* __restrict__ wfft, const float* __restrict__ bfft, const float* __restrict__ bnfft,
    const float* __restrict__ wdt1, const float* __restrict__ bdt1, const float* __restrict__ bndt1,
    const float* __restrict__ wdt2, const float* __restrict__ bdt2, const float* __restrict__ bndt2,
    char* __restrict__ ws)
{
  int i = blockIdx.x * 256 + threadIdx.x;
  unsigned short* WQS   = (unsigned short*)(ws + OFF_WQS);
  unsigned short* WQT   = (unsigned short*)(ws + OFF_WQT);
  unsigned short* WOUTS = (unsigned short*)(ws + OFF_WOUTS);
  unsigned short* WDS1  = (unsigned short*)(ws + OFF_WDS1);
  unsigned short* WFFS  = (unsigned short*)(ws + OFF_WFFS);
  unsigned short* WDS2  = (unsigned short*)(ws + OFF_WDS2);
  unsigned short* WOUTT = (unsigned short*)(ws + OFF_WOUTT);
  unsigned short* WDT1  = (unsigned short*)(ws + OFF_WDT1);
  unsigned short* WFFT  = (unsigned short*)(ws + OFF_WFFT);
  unsigned short* WDT2  = (unsigned short*)(ws + OFF_WDT2);
  float* SHS = (float*)(ws + OFF_SHS);
  float* SHT = (float*)(ws + OFF_SHT);
  float* SHA = (float*)(ws + OFF_SHA);
  float* SHB = (float*)(ws + OFF_SHB);
  float* SHC = (float*)(ws + OFF_SHC);
  float* SHD = (float*)(ws + OFF_SHD);

  if (i < 12288) { WQS[i] = f2bf(wqks[i]); }
  else if (i < 36864) { int j = i - 12288; WQT[j] = f2bf(wqkt[j]); }
  else if (i < 61440) { int j = i - 36864; int o = j / 192; WOUTS[j] = f2bf(wouts[j] * bnscale(bnouts, o)); }
  else if (i < 69632) { int j = i - 61440; int o = j / 64;  WDS1[j]  = f2bf(wds1[j]  * bnscale(bnds1, o)); }
  else if (i < 86016) { int j = i - 69632; int o = j / 128; WFFS[j]  = f2bf(wffs[j]  * bnscale(bnffs, o)); }
  else if (i < 94208) { int j = i - 86016; int o = j / 64;  WDS2[j]  = f2bf(wds2[j]  * bnscale(bnds2, o)); }
  else if (i < 143360){ int j = i - 94208; int o = j / 384; WOUTT[j] = f2bf(woutt[j] * bnscale(bnoutt, o)); }
  else if (i < 159744){ int j = i - 143360; int o = j / 128; WDT1[j] = f2bf(wdt1[j] * bnscale(bndt1, o)); }
  else if (i < 176128){ int j = i - 159744; int o = j / 128; WFFT[j] = f2bf(wfft[j] * bnscale(bnfft, o)); }
  else if (i < 192512){ int j = i - 176128; int o = j / 128; WDT2[j] = f2bf(wdt2[j] * bnscale(bndt2, o)); }
  else if (i < 198656){ // SHS[r][u]: bias + conv(pe_s)
    int j = i - 192512; int r = j >> 5, u = j & 31;
    float acc = 0.f;
    if (u < V_) {
      acc = bqks[r];
      const float inv = 2.0f * LN1E4 / (float)CIN;
      for (int c = 0; c < CIN; ++c) acc += wqks[r*CIN + c] * pe_val(c, u, inv);
    }
    SHS[j] = acc;
  }
  else if (i < 210944){ // SHT[r][t]
    int j = i - 198656; int r = j >> 6, t = j & 63;
    float acc = bqkt[r];
    const float inv = 2.0f * LN1E4 / (float)COUT;
    for (int c = 0; c < COUT; ++c) acc += wqkt[r*COUT + c] * pe_val(c, t, inv);
    SHT[j] = acc;
  }
  else if (i < 211456){
    int j = i - 210944; int o = j & 127; int g = j >> 7;
    if (g == 0) SHA[o] = bnshift(bnouts, bouts, o) + bnshift(bnds1, bds1, o);
    if (g == 1) SHB[o] = bnshift(bnffs, bffs, o)   + bnshift(bnds2, bds2, o);
    if (g == 2) SHC[o] = bnshift(bnoutt, boutt, o) + bnshift(bndt1, bdt1, o);
    if (g == 3) SHD[o] = bnshift(bnfft, bfft, o)   + bnshift(bndt2, bdt2, o);
  }
}

// =============================================================================
// convert x fp32 NCTV -> x_cl [pos][64] bf16
// =============================================================================
__global__ __launch_bounds__(256) void k_convert(const float* __restrict__ x,
                                                 unsigned short* __restrict__ xcl)
{
  __shared__ float xs[64][26];
  int b = blockIdx.x; int n = b >> 6, t = b & 63; int tid = threadIdx.x;
  for (int i = tid; i < 1600; i += 256) {
    int c = i / 25, v = i % 25;
    xs[c][v] = x[(((size_t)(n*64 + c))*64 + t)*25 + v];
  }
  __syncthreads();
  size_t clbase = ((size_t)(n*64 + t)) * 1600;
  for (int i = tid; i < 1600; i += 256) { int v = i >> 6, c = i & 63; xcl[clbase + i] = f2bf(xs[c][v]); }
}

// =============================================================================
// weights-in-LDS dual GEMM conv.  Block = 256 threads = 4 waves x 64 pos.
// out[pos][o] = f( A1[pos,:K1].W1[o]^T + A2[pos,:K2].W2[o]^T + shift )
// SMODE: 0 none, 1 shift[o*32+v], 2 shift[o*64+t], 3 shift[o]
// OMODE: 0 bf16 channel-last [pos][NO] ; 2 fp32 NCTV (NO==128)
// =============================================================================
template<int K1, int K2, int NO, int SMODE, int LRELU, int OMODE>
__global__ __launch_bounds__(256, 2) void k_conv(
    const unsigned short* __restrict__ A1, const unsigned short* __restrict__ A2,
    const unsigned short* __restrict__ W1, const unsigned short* __restrict__ W2,
    const float* __restrict__ shift, void* __restrict__ outp)
{
  constexpr int K   = K1 + K2;      // multiple of 64
  constexpr int NK  = K / 32;
  constexpr int NK1 = K1 / 32;
  constexpr int GR  = K / 8;        // 16B granules per row
  __shared__ __align__(16) unsigned short Wl[NO * K];

  // ---- stage weights to LDS (XOR-swizzled granules) ----
  for (int i = threadIdx.x; i < NO * GR; i += 256) {
    int o = i / GR, c = i % GR;
    int k = c * 8;
    const unsigned short* src = (k < K1) ? (W1 + (size_t)o * K1 + k)
                                         : (W2 + (size_t)o * K2 + (k - K1));
    int cs = c ^ (o & 7);
    *(int4*)&Wl[o * K + cs * 8] = *(const int4*)src;
  }

  const int lane = threadIdx.x & 63;
  const int wave = threadIdx.x >> 6;
  const int col  = lane & 15;
  const int quad = lane >> 4;
  const int pos0 = blockIdx.x * 256 + wave * 64;

  // ---- preload A fragments (4 m-tiles x NK) ----
  bf16x8 a[4][NK];
#pragma unroll
  for (int m = 0; m < 4; ++m) {
    const int pos = pos0 + m * 16 + col;
#pragma unroll
    for (int ks = 0; ks < NK; ++ks) {
      const unsigned short* p = (ks < NK1)
          ? (A1 + (size_t)pos * K1 + ks * 32)
          : (A2 + (size_t)pos * K2 + (ks - NK1) * 32);
      a[m][ks] = *(const bf16x8*)(p + quad * 8);
    }
  }

  // ---- store bases / shift indices per (m,r) ----
  int sb[4];
  int sidx[4][4];
#pragma unroll
  for (int m = 0; m < 4; ++m) {
    int pm = pos0 + m * 16 + quad * 4;
    if (OMODE == 0) sb[m] = pm * NO;
    else { int n = pm / 1600, rm = pm % 1600; sb[m] = n * 204800 + rm; }
#pragma unroll
    for (int r = 0; r < 4; ++r) {
      int pos = pm + r;
      if (SMODE == 1) sidx[m][r] = pos % 25;
      else if (SMODE == 2) sidx[m][r] = (pos % 1600) / 25;
      else sidx[m][r] = 0;
    }
  }

  __syncthreads();

  // ---- main loop over o-tiles ----
  for (int ot = 0; ot < NO / 16; ++ot) {
    const int orow = ot * 16 + col;
    f32x4 acc[4];
#pragma unroll
    for (int m = 0; m < 4; ++m) acc[m] = (f32x4){0.f, 0.f, 0.f, 0.f};
#pragma unroll
    for (int ks = 0; ks < NK; ++ks) {
      int cs = (ks * 4 + quad) ^ (col & 7);
      bf16x8 w = *(const bf16x8*)&Wl[orow * K + cs * 8];
#pragma unroll
      for (int m = 0; m < 4; ++m) acc[m] = MFMA(a[m][ks], w, acc[m]);
    }
    float sho = (SMODE == 3) ? shift[orow] : 0.f;
    if (OMODE == 2) {
      float* of = (float*)outp;
#pragma unroll
      for (int m = 0; m < 4; ++m) {
        float4 o4;
        float v0 = acc[m][0] + sho, v1 = acc[m][1] + sho, v2 = acc[m][2] + sho, v3 = acc[m][3] + sho;
        if (LRELU) {
          v0 = v0 >= 0.f ? v0 : 0.1f * v0; v1 = v1 >= 0.f ? v1 : 0.1f * v1;
          v2 = v2 >= 0.f ? v2 : 0.1f * v2; v3 = v3 >= 0.f ? v3 : 0.1f * v3;
        }
        o4.x = v0; o4.y = v1; o4.z = v2; o4.w = v3;
        *(float4*)&of[(size_t)sb[m] + (size_t)orow * 1600] = o4;
      }
    } else {
      unsigned short* oc = (unsigned short*)outp;
#pragma unroll
      for (int m = 0; m < 4; ++m)
#pragma unroll
        for (int r = 0; r < 4; ++r) {
          float sh;
          if (SMODE == 1)      sh = shift[orow * 32 + sidx[m][r]];
          else if (SMODE == 2) sh = shift[orow * 64 + sidx[m][r]];
          else                 sh = sho;
          float val = acc[m][r] + sh;
          if (LRELU) val = val >= 0.f ? val : 0.1f * val;
          oc[(size_t)(sb[m] + r * NO) + orow] = f2bf(val);
        }
    }
  }
}

// =============================================================================
// spatial attention logits: per (n,s) block, 4 waves x 16-t partials + reduce
// out: att_sT[n][s][v(32)][u(32)] bf16, tanh-scaled, u>=25 zeros, rows v<25
// =============================================================================
__global__ __launch_bounds__(256) void k_att_s(const unsigned short* __restrict__ qks,
                                               const float* __restrict__ alphas,
                                               const float* __restrict__ att0s,
                                               unsigned short* __restrict__ attsT)
{
  __shared__ float red[4][1024];
  int b = blockIdx.x; int n = b / 3, s = b % 3;
  int tid = threadIdx.x;
  int wave = tid >> 6, lane = tid & 63;
  int col = lane & 15, quad = lane >> 4;
  f32x4 acc[2][2];
#pragma unroll
  for (int a = 0; a < 2; ++a)
#pragma unroll
    for (int c = 0; c < 2; ++c) acc[a][c] = (f32x4){0.f, 0.f, 0.f, 0.f};

  for (int tt = 0; tt < 16; ++tt) {
    int t = wave * 16 + tt;
    size_t rowb = ((size_t)(n * 64 + t)) * 25;
    bf16x8 afr[2], bfr[2];
#pragma unroll
    for (int ut = 0; ut < 2; ++ut)
      afr[ut] = *(const bf16x8*)(qks + (rowb + ut * 16 + col) * 192 + s * 32 + quad * 8);
#pragma unroll
    for (int vt = 0; vt < 2; ++vt)
      bfr[vt] = *(const bf16x8*)(qks + (rowb + vt * 16 + col) * 192 + 96 + s * 32 + quad * 8);
#pragma unroll
    for (int ut = 0; ut < 2; ++ut)
#pragma unroll
      for (int vt = 0; vt < 2; ++vt)
        acc[ut][vt] = MFMA(afr[ut], bfr[vt], acc[ut][vt]);
  }
#pragma unroll
  for (int ut = 0; ut < 2; ++ut)
#pragma unroll
    for (int vt = 0; vt < 2; ++vt)
#pragma unroll
      for (int r = 0; r < 4; ++r)
        red[wave][(ut * 8 + vt * 4 + r) * 64 + lane] = acc[ut][vt][r];
  __syncthreads();

  float alpha = alphas[s];
  float4 r0 = *(const float4*)&red[0][tid * 4];
  float4 r1 = *(const float4*)&red[1][tid * 4];
  float4 r2 = *(const float4*)&red[2][tid * 4];
  float4 r3 = *(const float4*)&red[3][tid * 4];
  float sum4[4] = { r0.x + r1.x + r2.x + r3.x, r0.y + r1.y + r2.y + r3.y,
                    r0.z + r1.z + r2.z + r3.z, r0.w + r1.w + r2.w + r3.w };
#pragma unroll
  for (int k = 0; k < 4; ++k) {
    int slot = tid * 4 + k;
    int lane_l = slot & 63;
    int f = slot >> 6;
    int ut = f >> 3, vt = (f >> 2) & 1, r = f & 3;
    int u = ut * 16 + (lane_l >> 4) * 4 + r;
    int v = vt * 16 + (lane_l & 15);
    if (v < V_) {
      float val = 0.f;
      if (u < V_)
        val = tanhf(sum4[k] * (1.0f / 2048.0f)) * alpha + att0s[(s * 25 + u) * 25 + v];
      attsT[((size_t)((n * 3 + s) * 32) + v) * 32 + u] = f2bf(val);
    }
  }
}

// =============================================================================
// spatial einsum: per (n,t): ys[v][s*64+c] = sum_u att_sT[s][v][u] * x[c][t][u]
// x gathered from XCL (bf16 channel-last)
// =============================================================================
__global__ __launch_bounds__(64) void k_einsum_s(const unsigned short* __restrict__ xcl,
                                                 const unsigned short* __restrict__ attsT,
                                                 unsigned short* __restrict__ ys)
{
  int b = blockIdx.x; int n = b >> 6, t = b & 63;
  int lane = threadIdx.x; int col = lane & 15, quad = lane >> 4;
  bf16x8 bfr[4];
#pragma unroll
  for (int ct = 0; ct < 4; ++ct) {
    const unsigned short* base = xcl + ((size_t)(n * 64 + t) * 25) * 64 + ct * 16 + col;
    bf16x8 f;
#pragma unroll
    for (int j = 0; j < 8; ++j) {
      int u = quad * 8 + j;
      f[j] = (u < V_) ? (short)base[u * 64] : (short)0;
    }
    bfr[ct] = f;
  }
  size_t posbase = ((size_t)(n * 64 + t)) * 25;
#pragma unroll
  for (int s = 0; s < 3; ++s) {
    bf16x8 afr[2];
#pragma unroll
    for (int vt = 0; vt < 2; ++vt)
      afr[vt] = *(const bf16x8*)(attsT + ((size_t)((n * 3 + s) * 32) + vt * 16 + col) * 32 + quad * 8);
#pragma unroll
    for (int vt = 0; vt < 2; ++vt)
#pragma unroll
      for (int ct = 0; ct < 4; ++ct) {
        f32x4 acc = {0.f, 0.f, 0.f, 0.f};
        acc = MFMA(afr[vt], bfr[ct], acc);
#pragma unroll
        for (int r = 0; r < 4; ++r) {
          int v = vt * 16 + quad * 4 + r;
          if (v < V_)
            ys[(posbase + v) * 192 + s * 64 + ct * 16 + col] = f2bf(acc[r]);
        }
      }
  }
}

// =============================================================================
// temporal attention logits: per (n,s): C[t64][q64], K=(v25 x c32)
// out att_tT[n][s][q][t] bf16
// =============================================================================
__global__ __launch_bounds__(256) void k_att_t(const unsigned short* __restrict__ qkt,
                                               const float* __restrict__ alphat,
                                               const float* __restrict__ att0t,
                                               unsigned short* __restrict__ atttT)
{
  int b = blockIdx.x; int n = b / 3, s = b % 3;
  int wave = threadIdx.x >> 6; int lane = threadIdx.x & 63;
  int col = lane & 15, quad = lane >> 4;
  int mt = wave;
  f32x4 acc[4];
#pragma unroll
  for (int q = 0; q < 4; ++q) acc[q] = (f32x4){0.f, 0.f, 0.f, 0.f};

  for (int v = 0; v < V_; ++v) {
    bf16x8 a = *(const bf16x8*)(qkt + (((size_t)(n * 64 + mt * 16 + col)) * 25 + v) * 192 + s * 32 + quad * 8);
#pragma unroll
    for (int nt = 0; nt < 4; ++nt) {
      bf16x8 bb = *(const bf16x8*)(qkt + (((size_t)(n * 64 + nt * 16 + col)) * 25 + v) * 192 + 96 + s * 32 + quad * 8);
      acc[nt] = MFMA(a, bb, acc[nt]);
    }
  }
  float alpha = alphat[s];
#pragma unroll
  for (int nt = 0; nt < 4; ++nt)
#pragma unroll
    for (int r = 0; r < 4; ++r) {
      int ti = mt * 16 + quad * 4 + r;
      int q  = nt * 16 + col;
      float val = tanhf(acc[nt][r] * (1.0f / 800.0f)) * alpha + att0t[(s * 64 + ti) * 64 + q];
      atttT[((size_t)((n * 3 + s) * 64) + q) * 64 + ti] = f2bf(val);
    }
}

// =============================================================================
// fused temporal merge per (n,v), v2: no yT staging, swizzled z (48 KB LDS)
//   stage1: z[q][s*128+c] = sum_t y[c][t] * att_tT[s][q][t]  (y gathered direct)
//   stage2: z1[q][o] = lrelu( z.Woutt'^T + ycl.Wdt1'^T + shiftC )
// z swizzle: granule (8 shorts) g = sc>>3 at phys (g&~7) + ((g&7)^(q&7))
// =============================================================================
__global__ __launch_bounds__(256, 2) void k_fused(
    const unsigned short* __restrict__ ycl,
    const unsigned short* __restrict__ atttT,
    const unsigned short* __restrict__ Woutt, const unsigned short* __restrict__ Wdt1,
    const float* __restrict__ shiftC, unsigned short* __restrict__ z1)
{
  __shared__ unsigned short z[64 * 384];   // 49152 B -> 3 blocks/CU
  int b = blockIdx.x; int n = b / 25, v = b % 25;
  int wave = threadIdx.x >> 6; int lane = threadIdx.x & 63;
  int col = lane & 15, quad = lane >> 4;

  // stage 1: gather y A-frags (A[m=c][k=t]) straight from global
  bf16x8 ya[2][2];
#pragma unroll
  for (int ci = 0; ci < 2; ++ci) {
    int c = (wave * 2 + ci) * 16 + col;
#pragma unroll
    for (int kk = 0; kk < 2; ++kk) {
      bf16x8 f;
#pragma unroll
      for (int j = 0; j < 8; ++j) {
        int t = kk * 32 + quad * 8 + j;
        f[j] = (short)ycl[(((size_t)(n * 64 + t)) * 25 + v) * 128 + c];
      }
      ya[ci][kk] = f;
    }
  }
#pragma unroll
  for (int s = 0; s < 3; ++s) {
#pragma unroll
    for (int ci = 0; ci < 2; ++ci) {
      int ctg = wave * 2 + ci;
#pragma unroll
      for (int qt = 0; qt < 4; ++qt) {
        const unsigned short* bp = atttT + ((size_t)((n * 3 + s) * 64) + qt * 16 + col) * 64 + quad * 8;
        f32x4 acc = {0.f, 0.f, 0.f, 0.f};
        acc = MFMA(ya[ci][0], *(const bf16x8*)bp, acc);
        acc = MFMA(ya[ci][1], *(const bf16x8*)(bp + 32), acc);
        bf16x4 pk;
        pk[0] = f2bf(acc[0]); pk[1] = f2bf(acc[1]); pk[2] = f2bf(acc[2]); pk[3] = f2bf(acc[3]);
        int q  = qt * 16 + col;
        int sc = s * 128 + ctg * 16 + quad * 4;
        int g  = sc >> 3;
        int ph = q * 384 + ((g & ~7) + ((g & 7) ^ (q & 7))) * 8 + (sc & 7);
        *(bf16x4*)&z[ph] = pk;
      }
    }
  }
  __syncthreads();

  // stage 2
  f32x4 acc[2][4];
#pragma unroll
  for (int a = 0; a < 2; ++a)
#pragma unroll
    for (int q = 0; q < 4; ++q) acc[a][q] = (f32x4){0.f, 0.f, 0.f, 0.f};

  for (int ks = 0; ks < 12; ++ks) {
    bf16x8 afr[4];
#pragma unroll
    for (int qt = 0; qt < 4; ++qt) {
      int q = qt * 16 + col;
      int g = ks * 4 + quad;
      int ph = q * 384 + ((g & ~7) + ((g & 7) ^ (q & 7))) * 8;
      afr[qt] = *(const bf16x8*)&z[ph];
    }
#pragma unroll
    for (int oi = 0; oi < 2; ++oi) {
      int otg = wave * 2 + oi;
      bf16x8 bb = *(const bf16x8*)(Woutt + (size_t)(otg * 16 + col) * 384 + ks * 32 + quad * 8);
#pragma unroll
      for (int qt = 0; qt < 4; ++qt) acc[oi][qt] = MFMA(afr[qt], bb, acc[oi][qt]);
    }
  }
  for (int ks = 0; ks < 4; ++ks) {
    bf16x8 afr[4];
#pragma unroll
    for (int qt = 0; qt < 4; ++qt)
      afr[qt] = *(const bf16x8*)(ycl + (((size_t)(n * 64 + qt * 16 + col)) * 25 + v) * 128 + ks * 32 + quad * 8);
#pragma unroll
    for (int oi = 0; oi < 2; ++oi) {
      int otg = wave * 2 + oi;
      bf16x8 bb = *(const bf16x8*)(Wdt1 + (size_t)(otg * 16 + col) * 128 + ks * 32 + quad * 8);
#pragma unroll
      for (int qt = 0; qt < 4; ++qt) acc[oi][qt] = MFMA(afr[qt], bb, acc[oi][qt]);
    }
  }
#pragma unroll
  for (int oi = 0; oi < 2; ++oi) {
    int o = (wave * 2 + oi) * 16 + col;
    float sh = shiftC[o];
#pragma unroll
    for (int qt = 0; qt < 4; ++qt)
#pragma unroll
      for (int r = 0; r < 4; ++r) {
        int q = qt * 16 + quad * 4 + r;
        float val = acc[oi][qt][r] + sh;
        val = (val >= 0.f) ? val : 0.1f * val;
        z1[(((size_t)(n * 64 + q)) * 25 + v) * 128 + o] = f2bf(val);
      }
  }
}

// =============================================================================
extern "C" void kernel_launch(void* const* d_in, const int* in_sizes, int n_in,
                              void* d_out, int out_size, void* d_ws, size_t ws_size,
                              hipStream_t stream)
{
  const float* x       = (const float*)d_in[0];
  const float* w_qk_s  = (const float*)d_in[1];
  const float* b_qk_s  = (const float*)d_in[2];
  const float* alphas  = (const float*)d_in[3];
  const float* att0s   = (const float*)d_in[4];
  const float* w_outs  = (const float*)d_in[5];
  const float* b_outs  = (const float*)d_in[6];
  const float* bn_outs = (const float*)d_in[7];
  const float* w_ffs   = (const float*)d_in[8];
  const float* b_ffs   = (const float*)d_in[9];
  const float* bn_ffs  = (const float*)d_in[10];
  const float* w_ds1   = (const float*)d_in[11];
  const float* b_ds1   = (const float*)d_in[12];
  const float* bn_ds1  = (const float*)d_in[13];
  const float* w_ds2   = (const float*)d_in[14];
  const float* b_ds2   = (const float*)d_in[15];
  const float* bn_ds2  = (const float*)d_in[16];
  const float* w_qk_t  = (const float*)d_in[17];
  const float* b_qk_t  = (const float*)d_in[18];
  const float* alphat  = (const float*)d_in[19];
  const float* att0t   = (const float*)d_in[20];
  const float* w_outt  = (const float*)d_in[21];
  const float* b_outt  = (const float*)d_in[22];
  const float* bn_outt = (const float*)d_in[23];
  const float* w_fft   = (const float*)d_in[24];
  const float* b_fft   = (const float*)d_in[25];
  const float* bn_fft  = (const float*)d_in[26];
  const float* w_dt1   = (const float*)d_in[27];
  const float* b_dt1   = (const float*)d_in[28];
  const float* bn_dt1  = (const float*)d_in[29];
  const float* w_dt2   = (const float*)d_in[30];
  const float* b_dt2   = (const float*)d_in[31];
  const float* bn_dt2  = (const float*)d_in[32];

  char* ws = (char*)d_ws;
  unsigned short* WQS   = (unsigned short*)(ws + OFF_WQS);
  unsigned short* WQT   = (unsigned short*)(ws + OFF_WQT);
  unsigned short* WOUTS = (unsigned short*)(ws + OFF_WOUTS);
  unsigned short* WDS1  = (unsigned short*)(ws + OFF_WDS1);
  unsigned short* WFFS  = (unsigned short*)(ws + OFF_WFFS);
  unsigned short* WDS2  = (unsigned short*)(ws + OFF_WDS2);
  unsigned short* WOUTT = (unsigned short*)(ws + OFF_WOUTT);
  unsigned short* WDT1  = (unsigned short*)(ws + OFF_WDT1);
  unsigned short* WFFT  = (unsigned short*)(ws + OFF_WFFT);
  unsigned short* WDT2  = (unsigned short*)(ws + OFF_WDT2);
  float* SHS = (float*)(ws + OFF_SHS);
  float* SHT = (float*)(ws + OFF_SHT);
  float* SHA = (float*)(ws + OFF_SHA);
  float* SHB = (float*)(ws + OFF_SHB);
  float* SHC = (float*)(ws + OFF_SHC);
  float* SHD = (float*)(ws + OFF_SHD);
  unsigned short* ATTST = (unsigned short*)(ws + OFF_ATTST);
  unsigned short* ATTTT = (unsigned short*)(ws + OFF_ATTTT);
  unsigned short* XCL   = (unsigned short*)(ws + OFF_XCL);
  unsigned short* YCL   = (unsigned short*)(ws + OFF_YCL);
  unsigned short* RB    = (unsigned short*)(ws + OFF_RB);
  unsigned short* RA    = (unsigned short*)(ws + OFF_RA);

  k_prep<<<826, 256, 0, stream>>>(
      w_qk_s, b_qk_s, w_outs, b_outs, bn_outs, w_ffs, b_ffs, bn_ffs,
      w_ds1, b_ds1, bn_ds1, w_ds2, b_ds2, bn_ds2, w_qk_t, b_qk_t,
      w_outt, b_outt, bn_outt, w_fft, b_fft, bn_fft,
      w_dt1, b_dt1, bn_dt1, w_dt2, b_dt2, bn_dt2, ws);

  k_convert<<<N_ * T_, 256, 0, stream>>>(x, XCL);

  // qk_s: RA[pos][192] = XCL.WQS^T + SHS[o][v]
  k_conv<64, 0, 192, 1, 0, 0><<<P_ / 256, 256, 0, stream>>>(
      XCL, (const unsigned short*)nullptr, WQS, (const unsigned short*)nullptr, SHS, RA);

  k_att_s<<<N_ * S_, 256, 0, stream>>>(RA, alphas, att0s, ATTST);
  // ys -> RA (qk_s dead)
  k_einsum_s<<<N_ * T_, 64, 0, stream>>>(XCL, ATTST, RA);

  // y1 = lrelu(outs(ys) + ds1(x)) -> RB
  k_conv<192, 64, 128, 3, 1, 0><<<P_ / 256, 256, 0, stream>>>(
      RA, XCL, WOUTS, WDS1, SHA, RB);

  // y = lrelu(ffs(y1) + ds2(x)) -> YCL
  k_conv<128, 64, 128, 3, 1, 0><<<P_ / 256, 256, 0, stream>>>(
      RB, XCL, WFFS, WDS2, SHB, YCL);

  // qk_t: RA[pos][192] = YCL.WQT^T + SHT[o][t]
  k_conv<128, 0, 192, 2, 0, 0><<<P_ / 256, 256, 0, stream>>>(
      YCL, (const unsigned short*)nullptr, WQT, (const unsigned short*)nullptr, SHT, RA);

  k_att_t<<<N_ * S_, 256, 0, stream>>>(RA, alphat, att0t, ATTTT);

  // z1 = lrelu(outt(einsum_t(y,att)) + dt1(y)) -> RB (y1 dead)
  k_fused<<<N_ * V_, 256, 0, stream>>>(YCL, ATTTT, WOUTT, WDT1, SHC, RB);

  // out = lrelu(fft(z1) + dt2(y)), fp32 NCTV
  k_conv<128, 128, 128, 3, 1, 2><<<P_ / 256, 256, 0, stream>>>(
      RB, YCL, WFFT, WDT2, SHD, d_out);
}

// Round 6
// 673.795 us; speedup vs baseline: 1.2088x; 1.2088x over previous
//
#include <hip/hip_runtime.h>
#include <math.h>

#define N_    128
#define CIN   64
#define COUT  128
#define CINT  32
#define S_    3
#define T_    64
#define V_    25
#define EPSF  1e-5f
#define LN1E4 9.210340371976184f
#define P_    (N_*T_*V_)   // 204800 positions

typedef __attribute__((ext_vector_type(8))) short bf16x8;
typedef __attribute__((ext_vector_type(4))) unsigned short bf16x4;
typedef __attribute__((ext_vector_type(4))) float f32x4;

#define MFMA(a,b,c) __builtin_amdgcn_mfma_f32_16x16x32_bf16(a,b,c,0,0,0)

// ---- workspace byte offsets (round-4 verified map) ---------------------------
#define OFF_WQS    0u          // 192x64 bf16           -> 24576
#define OFF_WQT    24576u      // 192x128               -> 73728
#define OFF_WOUTS  73728u      // 128x192 prescaled     -> 122880
#define OFF_WDS1   122880u     // 128x64                -> 139264
#define OFF_WFFS   139264u     // 128x128               -> 172032
#define OFF_WDS2   172032u     // 128x64                -> 188416
#define OFF_WOUTT  188416u     // 128x384               -> 286720
#define OFF_WDT1   286720u     // 128x128               -> 319488
#define OFF_WFFT   319488u     // 128x128               -> 352256
#define OFF_WDT2   352256u     // 128x128               -> 385024
#define OFF_WOV    385024u     // 192x64 bf16 (qk_s shift cols) -> 409600
#define OFF_WOT    409600u     // 192x64 bf16 (qk_t shift cols) -> 434176
#define OFF_SHA    434176u
#define OFF_SHB    434688u
#define OFF_SHC    435200u
#define OFF_SHD    435712u     //                       -> 436224
#define OFF_OV     436224u     // [1600][64] onehot(v) bf16 -> 641024
#define OFF_OT     641024u     // [1600][64] onehot(t) bf16 -> 845824
#define OFF_ATTST  845824u     // [n][s][32v][32u] bf16 -> 1632256
#define OFF_ATTTT  1632256u    // [n][s][64q][64t] bf16 -> 4777984
#define OFF_XCL    4777984u    // [pos][64]  bf16       -> 30992384
#define OFF_YCL    30992384u   // [pos][128] bf16 (y)   -> 83421184
#define OFF_RB     83421184u   // [pos][128] bf16 (y1 then z1) -> 135849984
#define OFF_RA     135849984u  // [pos][192] bf16 (qk_s -> ys -> qk_t) -> 214493184

__device__ __forceinline__ unsigned short f2bf(float f) {
  union { float f; unsigned int u; } v; v.f = f;
  unsigned int u = v.u;
  return (unsigned short)((u + 0x7FFFu + ((u >> 16) & 1u)) >> 16);
}
__device__ __forceinline__ float bnscale(const float* bn, int o) {
  return bn[o] * rsqrtf(bn[3*COUT + o] + EPSF);
}
__device__ __forceinline__ float bnshift(const float* bn, const float* b, int o) {
  return (b[o] - bn[2*COUT + o]) * bnscale(bn, o) + bn[COUT + o];
}
__device__ __forceinline__ float pe_val(int c, int p, float inv) {
  float freq = expf(-(float)(c >> 1) * inv);
  float arg = (float)p * freq;
  return (c & 1) ? cosf(arg) : sinf(arg);
}

// =============================================================================
// prep (round-4 verified): bf16 BN-prescaled weights, shift-folded weight cols,
// onehot tables
// =============================================================================
__global__ __launch_bounds__(256) void k_prep(
    const float* __restrict__ wqks, const float* __restrict__ bqks,
    const float* __restrict__ wouts, const float* __restrict__ bouts, const float* __restrict__ bnouts,
    const float* __restrict__ wffs, const float* __restrict__ bffs, const float* __restrict__ bnffs,
    const float* __restrict__ wds1, const float* __restrict__ bds1, const float* __restrict__ bnds1,
    const float* __restrict__ wds2, const float* __restrict__ bds2, const float* __restrict__ bnds2,
    const float* __restrict__ wqkt, const float* __restrict__ bqkt,
    const float* __restrict__ woutt, const float* __restrict__ boutt, const float* __restrict__ bnoutt,
    const float* __restrict__ wfft, const float* __restrict__ bfft, const float* __restrict__ bnfft,
    const float* __restrict__ wdt1, const float* __restrict__ bdt1, const float* __restrict__ bndt1,
    const float* __restrict__ wdt2, const float* __restrict__ bdt2, const float* __restrict__ bndt2,
    char* __restrict__ ws)
{
  int i = blockIdx.x * 256 + threadIdx.x;
  unsigned short* WQS   = (unsigned short*)(ws + OFF_WQS);
  unsigned short* WQT   = (unsigned short*)(ws + OFF_WQT);
  unsigned short* WOUTS = (unsigned short*)(ws + OFF_WOUTS);
  unsigned short* WDS1  = (unsigned short*)(ws + OFF_WDS1);
  unsigned short* WFFS  = (unsigned short*)(ws + OFF_WFFS);
  unsigned short* WDS2  = (unsigned short*)(ws + OFF_WDS2);
  unsigned short* WOUTT = (unsigned short*)(ws + OFF_WOUTT);
  unsigned short* WDT1  = (unsigned short*)(ws + OFF_WDT1);
  unsigned short* WFFT  = (unsigned short*)(ws + OFF_WFFT);
  unsigned short* WDT2  = (unsigned short*)(ws + OFF_WDT2);
  unsigned short* WOV   = (unsigned short*)(ws + OFF_WOV);
  unsigned short* WOT   = (unsigned short*)(ws + OFF_WOT);
  float* SHA = (float*)(ws + OFF_SHA);
  float* SHB = (float*)(ws + OFF_SHB);
  float* SHC = (float*)(ws + OFF_SHC);
  float* SHD = (float*)(ws + OFF_SHD);
  unsigned short* OV = (unsigned short*)(ws + OFF_OV);
  unsigned short* OT = (unsigned short*)(ws + OFF_OT);

  if (i < 12288) { WQS[i] = f2bf(wqks[i]); }
  else if (i < 36864) { int j = i - 12288; WQT[j] = f2bf(wqkt[j]); }
  else if (i < 61440) { int j = i - 36864; int o = j / 192; WOUTS[j] = f2bf(wouts[j] * bnscale(bnouts, o)); }
  else if (i < 69632) { int j = i - 61440; int o = j / 64;  WDS1[j]  = f2bf(wds1[j]  * bnscale(bnds1, o)); }
  else if (i < 86016) { int j = i - 69632; int o = j / 128; WFFS[j]  = f2bf(wffs[j]  * bnscale(bnffs, o)); }
  else if (i < 94208) { int j = i - 86016; int o = j / 64;  WDS2[j]  = f2bf(wds2[j]  * bnscale(bnds2, o)); }
  else if (i < 143360){ int j = i - 94208; int o = j / 384; WOUTT[j] = f2bf(woutt[j] * bnscale(bnoutt, o)); }
  else if (i < 159744){ int j = i - 143360; int o = j / 128; WDT1[j] = f2bf(wdt1[j] * bnscale(bndt1, o)); }
  else if (i < 176128){ int j = i - 159744; int o = j / 128; WFFT[j] = f2bf(wfft[j] * bnscale(bnfft, o)); }
  else if (i < 192512){ int j = i - 176128; int o = j / 128; WDT2[j] = f2bf(wdt2[j] * bnscale(bndt2, o)); }
  else if (i < 204800){ // WOV[o][u]: qk_s shift (bias + conv(pe_s)) as weight cols
    int j = i - 192512; int o = j >> 6, u = j & 63;
    float acc = 0.f;
    if (u < V_) {
      acc = bqks[o];
      const float inv = 2.0f * LN1E4 / (float)CIN;
      for (int c = 0; c < CIN; ++c) acc += wqks[o*CIN + c] * pe_val(c, u, inv);
    }
    WOV[j] = f2bf(acc);
  }
  else if (i < 217088){ // WOT[o][t]: qk_t shift
    int j = i - 204800; int o = j >> 6, t = j & 63;
    float acc = bqkt[o];
    const float inv = 2.0f * LN1E4 / (float)COUT;
    for (int c = 0; c < COUT; ++c) acc += wqkt[o*COUT + c] * pe_val(c, t, inv);
    WOT[j] = f2bf(acc);
  }
  else if (i < 217600){
    int j = i - 217088; int o = j & 127; int g = j >> 7;
    if (g == 0) SHA[o] = bnshift(bnouts, bouts, o) + bnshift(bnds1, bds1, o);
    if (g == 1) SHB[o] = bnshift(bnffs, bffs, o)   + bnshift(bnds2, bds2, o);
    if (g == 2) SHC[o] = bnshift(bnoutt, boutt, o) + bnshift(bndt1, bdt1, o);
    if (g == 3) SHD[o] = bnshift(bnfft, bfft, o)   + bnshift(bndt2, bdt2, o);
  }
  else if (i < 320000){ // OV[rem][u] = onehot(v)
    int j = i - 217600; int rem = j >> 6, u = j & 63;
    OV[j] = (u == rem % 25) ? (unsigned short)0x3F80 : (unsigned short)0;
  }
  else if (i < 422400){ // OT[rem][u] = onehot(t)
    int j = i - 320000; int rem = j >> 6, u = j & 63;
    OT[j] = (u == rem / 25) ? (unsigned short)0x3F80 : (unsigned short)0;
  }
}

// =============================================================================
// convert x fp32 NCTV -> x_cl [pos][64] bf16
// =============================================================================
__global__ __launch_bounds__(256) void k_convert(const float* __restrict__ x,
                                                 unsigned short* __restrict__ xcl)
{
  __shared__ float xs[64][26];
  int b = blockIdx.x; int n = b >> 6, t = b & 63; int tid = threadIdx.x;
  for (int i = tid; i < 1600; i += 256) {
    int c = i / 25, v = i % 25;
    xs[c][v] = x[(((size_t)(n*64 + c))*64 + t)*25 + v];
  }
  __syncthreads();
  size_t clbase = ((size_t)(n*64 + t)) * 1600;
  for (int i = tid; i < 1600; i += 256) { int v = i >> 6, c = i & 63; xcl[clbase + i] = f2bf(xs[c][v]); }
}

// =============================================================================
// weights-in-LDS dual GEMM conv (round-4 verified).  256 thr = 4 waves x 64 pos.
// out[pos][o] = f( A1[pos,:K1].W1[o]^T + A2[row2,:K2].W2[o]^T (+ shift[o]) )
// A2MOD: row2 = pos % 1600 (onehot tables) else pos.
// OMODE: 0 bf16 CL [pos][NOFULL] ; 2 fp32 NCTV (NOSUB==NOFULL==128)
// grid = (P_/256, NOFULL/NOSUB)
// =============================================================================
template<int K1, int K2, int NOSUB, int NOFULL, int HASSHIFT, int LRELU, int OMODE, int A2MOD>
__global__ __launch_bounds__(256, 2) void k_conv(
    const unsigned short* __restrict__ A1, const unsigned short* __restrict__ A2,
    const unsigned short* __restrict__ W1, const unsigned short* __restrict__ W2,
    const float* __restrict__ shift, void* __restrict__ outp)
{
  constexpr int K   = K1 + K2;      // multiple of 64
  constexpr int NK  = K / 32;
  constexpr int NK1 = K1 / 32;
  constexpr int GR  = K / 8;        // 16B granules per row
  __shared__ __align__(16) unsigned short Wl[NOSUB * K];

  const int oy = blockIdx.y;
  // ---- stage weights to LDS (XOR-swizzled granules) ----
  for (int i = threadIdx.x; i < NOSUB * GR; i += 256) {
    int o = i / GR, c = i % GR;
    int og = oy * NOSUB + o;
    int k = c * 8;
    const unsigned short* src = (k < K1) ? (W1 + (size_t)og * K1 + k)
                                         : (W2 + (size_t)og * K2 + (k - K1));
    int cs = c ^ (o & 7);
    *(int4*)&Wl[o * K + cs * 8] = *(const int4*)src;
  }

  const int lane = threadIdx.x & 63;
  const int wave = threadIdx.x >> 6;
  const int col  = lane & 15;
  const int quad = lane >> 4;
  const int pos0 = blockIdx.x * 256 + wave * 64;

  // ---- preload A fragments (4 m-tiles x NK) ----
  bf16x8 a[4][NK];
  const int remw = pos0 % 1600;
#pragma unroll
  for (int m = 0; m < 4; ++m) {
    const int pos = pos0 + m * 16 + col;
#pragma unroll
    for (int ks = 0; ks < NK; ++ks) {
      const unsigned short* p;
      if (ks < NK1) {
        p = A1 + (size_t)pos * K1 + ks * 32;
      } else {
        int row = pos;
        if (A2MOD) { int r2 = remw + m * 16 + col; if (r2 >= 1600) r2 -= 1600; row = r2; }
        p = A2 + (size_t)row * K2 + (ks - NK1) * 32;
      }
      a[m][ks] = *(const bf16x8*)(p + quad * 8);
    }
  }

  // ---- store bases per m ----
  int sb[4];
#pragma unroll
  for (int m = 0; m < 4; ++m) {
    int pm = pos0 + m * 16 + quad * 4;
    if (OMODE == 0) sb[m] = pm * NOFULL + oy * NOSUB + col;
    else { int n = pm / 1600, rm = pm % 1600; sb[m] = n * 204800 + rm; }
  }

  __syncthreads();

  // ---- main loop over o-tiles ----
  for (int ot = 0; ot < NOSUB / 16; ++ot) {
    const int orow = ot * 16 + col;
    f32x4 acc[4];
#pragma unroll
    for (int m = 0; m < 4; ++m) acc[m] = (f32x4){0.f, 0.f, 0.f, 0.f};
#pragma unroll
    for (int ks = 0; ks < NK; ++ks) {
      int cs = (ks * 4 + quad) ^ (col & 7);
      bf16x8 w = *(const bf16x8*)&Wl[orow * K + cs * 8];
#pragma unroll
      for (int m = 0; m < 4; ++m) acc[m] = MFMA(a[m][ks], w, acc[m]);
    }
    float sh = 0.f;
    if (HASSHIFT) sh = shift[oy * NOSUB + orow];
    if (OMODE == 2) {
      float* of = (float*)outp;
#pragma unroll
      for (int m = 0; m < 4; ++m) {
        float4 o4;
        float v0 = acc[m][0] + sh, v1 = acc[m][1] + sh, v2 = acc[m][2] + sh, v3 = acc[m][3] + sh;
        if (LRELU) {
          v0 = v0 >= 0.f ? v0 : 0.1f * v0; v1 = v1 >= 0.f ? v1 : 0.1f * v1;
          v2 = v2 >= 0.f ? v2 : 0.1f * v2; v3 = v3 >= 0.f ? v3 : 0.1f * v3;
        }
        o4.x = v0; o4.y = v1; o4.z = v2; o4.w = v3;
        *(float4*)&of[(size_t)sb[m] + (size_t)orow * 1600] = o4;
      }
    } else {
      unsigned short* oc = (unsigned short*)outp;
#pragma unroll
      for (int m = 0; m < 4; ++m)
#pragma unroll
        for (int r = 0; r < 4; ++r) {
          float val = acc[m][r] + sh;
          if (LRELU) val = val >= 0.f ? val : 0.1f * val;
          oc[(size_t)(sb[m] + r * NOFULL) + ot * 16] = f2bf(val);
        }
    }
  }
}

// =============================================================================
// spatial attention logits: per (n,s) block, 4 waves x 16-t partials + reduce
// out: att_sT[n][s][v(32)][u(32)] bf16, tanh-scaled, u>=25 zeros, rows v<25
// =============================================================================
__global__ __launch_bounds__(256) void k_att_s(const unsigned short* __restrict__ qks,
                                               const float* __restrict__ alphas,
                                               const float* __restrict__ att0s,
                                               unsigned short* __restrict__ attsT)
{
  __shared__ float red[4][1024];
  int b = blockIdx.x; int n = b / 3, s = b % 3;
  int tid = threadIdx.x;
  int wave = tid >> 6, lane = tid & 63;
  int col = lane & 15, quad = lane >> 4;
  f32x4 acc[2][2];
#pragma unroll
  for (int a = 0; a < 2; ++a)
#pragma unroll
    for (int c = 0; c < 2; ++c) acc[a][c] = (f32x4){0.f, 0.f, 0.f, 0.f};

  for (int tt = 0; tt < 16; ++tt) {
    int t = wave * 16 + tt;
    size_t rowb = ((size_t)(n * 64 + t)) * 25;
    bf16x8 afr[2], bfr[2];
#pragma unroll
    for (int ut = 0; ut < 2; ++ut)
      afr[ut] = *(const bf16x8*)(qks + (rowb + ut * 16 + col) * 192 + s * 32 + quad * 8);
#pragma unroll
    for (int vt = 0; vt < 2; ++vt)
      bfr[vt] = *(const bf16x8*)(qks + (rowb + vt * 16 + col) * 192 + 96 + s * 32 + quad * 8);
#pragma unroll
    for (int ut = 0; ut < 2; ++ut)
#pragma unroll
      for (int vt = 0; vt < 2; ++vt)
        acc[ut][vt] = MFMA(afr[ut], bfr[vt], acc[ut][vt]);
  }
#pragma unroll
  for (int ut = 0; ut < 2; ++ut)
#pragma unroll
    for (int vt = 0; vt < 2; ++vt)
#pragma unroll
      for (int r = 0; r < 4; ++r)
        red[wave][(ut * 8 + vt * 4 + r) * 64 + lane] = acc[ut][vt][r];
  __syncthreads();

  float alpha = alphas[s];
  float4 r0 = *(const float4*)&red[0][tid * 4];
  float4 r1 = *(const float4*)&red[1][tid * 4];
  float4 r2 = *(const float4*)&red[2][tid * 4];
  float4 r3 = *(const float4*)&red[3][tid * 4];
  float sum4[4] = { r0.x + r1.x + r2.x + r3.x, r0.y + r1.y + r2.y + r3.y,
                    r0.z + r1.z + r2.z + r3.z, r0.w + r1.w + r2.w + r3.w };
#pragma unroll
  for (int k = 0; k < 4; ++k) {
    int slot = tid * 4 + k;
    int lane_l = slot & 63;
    int f = slot >> 6;
    int ut = f >> 3, vt = (f >> 2) & 1, r = f & 3;
    int u = ut * 16 + (lane_l >> 4) * 4 + r;
    int v = vt * 16 + (lane_l & 15);
    if (v < V_) {
      float val = 0.f;
      if (u < V_)
        val = tanhf(sum4[k] * (1.0f / 2048.0f)) * alpha + att0s[(s * 25 + u) * 25 + v];
      attsT[((size_t)((n * 3 + s) * 32) + v) * 32 + u] = f2bf(val);
    }
  }
}

// =============================================================================
// spatial einsum: per (n,t): ys[v][s*64+c] = sum_u att_sT[s][v][u] * x[c][t][u]
// x gathered from XCL (bf16 channel-last)
// =============================================================================
__global__ __launch_bounds__(64) void k_einsum_s(const unsigned short* __restrict__ xcl,
                                                 const unsigned short* __restrict__ attsT,
                                                 unsigned short* __restrict__ ys)
{
  int b = blockIdx.x; int n = b >> 6, t = b & 63;
  int lane = threadIdx.x; int col = lane & 15, quad = lane >> 4;
  bf16x8 bfr[4];
#pragma unroll
  for (int ct = 0; ct < 4; ++ct) {
    const unsigned short* base = xcl + ((size_t)(n * 64 + t) * 25) * 64 + ct * 16 + col;
    bf16x8 f;
#pragma unroll
    for (int j = 0; j < 8; ++j) {
      int u = quad * 8 + j;
      f[j] = (u < V_) ? (short)base[u * 64] : (short)0;
    }
    bfr[ct] = f;
  }
  size_t posbase = ((size_t)(n * 64 + t)) * 25;
#pragma unroll
  for (int s = 0; s < 3; ++s) {
    bf16x8 afr[2];
#pragma unroll
    for (int vt = 0; vt < 2; ++vt)
      afr[vt] = *(const bf16x8*)(attsT + ((size_t)((n * 3 + s) * 32) + vt * 16 + col) * 32 + quad * 8);
#pragma unroll
    for (int vt = 0; vt < 2; ++vt)
#pragma unroll
      for (int ct = 0; ct < 4; ++ct) {
        f32x4 acc = {0.f, 0.f, 0.f, 0.f};
        acc = MFMA(afr[vt], bfr[ct], acc);
#pragma unroll
        for (int r = 0; r < 4; ++r) {
          int v = vt * 16 + quad * 4 + r;
          if (v < V_)
            ys[(posbase + v) * 192 + s * 64 + ct * 16 + col] = f2bf(acc[r]);
        }
      }
  }
}

// =============================================================================
// temporal attention logits: per (n,s): C[t64][q64], K=(v25 x c32)
// out att_tT[n][s][q][t] bf16
// =============================================================================
__global__ __launch_bounds__(256) void k_att_t(const unsigned short* __restrict__ qkt,
                                               const float* __restrict__ alphat,
                                               const float* __restrict__ att0t,
                                               unsigned short* __restrict__ atttT)
{
  int b = blockIdx.x; int n = b / 3, s = b % 3;
  int wave = threadIdx.x >> 6; int lane = threadIdx.x & 63;
  int col = lane & 15, quad = lane >> 4;
  int mt = wave;
  f32x4 acc[4];
#pragma unroll
  for (int q = 0; q < 4; ++q) acc[q] = (f32x4){0.f, 0.f, 0.f, 0.f};

  for (int v = 0; v < V_; ++v) {
    bf16x8 a = *(const bf16x8*)(qkt + (((size_t)(n * 64 + mt * 16 + col)) * 25 + v) * 192 + s * 32 + quad * 8);
#pragma unroll
    for (int nt = 0; nt < 4; ++nt) {
      bf16x8 bb = *(const bf16x8*)(qkt + (((size_t)(n * 64 + nt * 16 + col)) * 25 + v) * 192 + 96 + s * 32 + quad * 8);
      acc[nt] = MFMA(a, bb, acc[nt]);
    }
  }
  float alpha = alphat[s];
#pragma unroll
  for (int nt = 0; nt < 4; ++nt)
#pragma unroll
    for (int r = 0; r < 4; ++r) {
      int ti = mt * 16 + quad * 4 + r;
      int q  = nt * 16 + col;
      float val = tanhf(acc[nt][r] * (1.0f / 800.0f)) * alpha + att0t[(s * 64 + ti) * 64 + q];
      atttT[((size_t)((n * 3 + s) * 64) + q) * 64 + ti] = f2bf(val);
    }
}

// =============================================================================
// fused temporal merge per (n,v), v2 (round-5 verified): no yT staging,
// swizzled z (48 KB LDS)
// =============================================================================
__global__ __launch_bounds__(256, 2) void k_fused(
    const unsigned short* __restrict__ ycl,
    const unsigned short* __restrict__ atttT,
    const unsigned short* __restrict__ Woutt, const unsigned short* __restrict__ Wdt1,
    const float* __restrict__ shiftC, unsigned short* __restrict__ z1)
{
  __shared__ unsigned short z[64 * 384];   // 49152 B -> 3 blocks/CU
  int b = blockIdx.x; int n = b / 25, v = b % 25;
  int wave = threadIdx.x >> 6; int lane = threadIdx.x & 63;
  int col = lane & 15, quad = lane >> 4;

  // stage 1: gather y A-frags (A[m=c][k=t]) straight from global
  bf16x8 ya[2][2];
#pragma unroll
  for (int ci = 0; ci < 2; ++ci) {
    int c = (wave * 2 + ci) * 16 + col;
#pragma unroll
    for (int kk = 0; kk < 2; ++kk) {
      bf16x8 f;
#pragma unroll
      for (int j = 0; j < 8; ++j) {
        int t = kk * 32 + quad * 8 + j;
        f[j] = (short)ycl[(((size_t)(n * 64 + t)) * 25 + v) * 128 + c];
      }
      ya[ci][kk] = f;
    }
  }
#pragma unroll
  for (int s = 0; s < 3; ++s) {
#pragma unroll
    for (int ci = 0; ci < 2; ++ci) {
      int ctg = wave * 2 + ci;
#pragma unroll
      for (int qt = 0; qt < 4; ++qt) {
        const unsigned short* bp = atttT + ((size_t)((n * 3 + s) * 64) + qt * 16 + col) * 64 + quad * 8;
        f32x4 acc = {0.f, 0.f, 0.f, 0.f};
        acc = MFMA(ya[ci][0], *(const bf16x8*)bp, acc);
        acc = MFMA(ya[ci][1], *(const bf16x8*)(bp + 32), acc);
        bf16x4 pk;
        pk[0] = f2bf(acc[0]); pk[1] = f2bf(acc[1]); pk[2] = f2bf(acc[2]); pk[3] = f2bf(acc[3]);
        int q  = qt * 16 + col;
        int sc = s * 128 + ctg * 16 + quad * 4;
        int g  = sc >> 3;
        int ph = q * 384 + ((g & ~7) + ((g & 7) ^ (q & 7))) * 8 + (sc & 7);
        *(bf16x4*)&z[ph] = pk;
      }
    }
  }
  __syncthreads();

  // stage 2
  f32x4 acc[2][4];
#pragma unroll
  for (int a = 0; a < 2; ++a)
#pragma unroll
    for (int q = 0; q < 4; ++q) acc[a][q] = (f32x4){0.f, 0.f, 0.f, 0.f};

  for (int ks = 0; ks < 12; ++ks) {
    bf16x8 afr[4];
#pragma unroll
    for (int qt = 0; qt < 4; ++qt) {
      int q = qt * 16 + col;
      int g = ks * 4 + quad;
      int ph = q * 384 + ((g & ~7) + ((g & 7) ^ (q & 7))) * 8;
      afr[qt] = *(const bf16x8*)&z[ph];
    }
#pragma unroll
    for (int oi = 0; oi < 2; ++oi) {
      int otg = wave * 2 + oi;
      bf16x8 bb = *(const bf16x8*)(Woutt + (size_t)(otg * 16 + col) * 384 + ks * 32 + quad * 8);
#pragma unroll
      for (int qt = 0; qt < 4; ++qt) acc[oi][qt] = MFMA(afr[qt], bb, acc[oi][qt]);
    }
  }
  for (int ks = 0; ks < 4; ++ks) {
    bf16x8 afr[4];
#pragma unroll
    for (int qt = 0; qt < 4; ++qt)
      afr[qt] = *(const bf16x8*)(ycl + (((size_t)(n * 64 + qt * 16 + col)) * 25 + v) * 128 + ks * 32 + quad * 8);
#pragma unroll
    for (int oi = 0; oi < 2; ++oi) {
      int otg = wave * 2 + oi;
      bf16x8 bb = *(const bf16x8*)(Wdt1 + (size_t)(otg * 16 + col) * 128 + ks * 32 + quad * 8);
#pragma unroll
      for (int qt = 0; qt < 4; ++qt) acc[oi][qt] = MFMA(afr[qt], bb, acc[oi][qt]);
    }
  }
#pragma unroll
  for (int oi = 0; oi < 2; ++oi) {
    int o = (wave * 2 + oi) * 16 + col;
    float sh = shiftC[o];
#pragma unroll
    for (int qt = 0; qt < 4; ++qt)
#pragma unroll
      for (int r = 0; r < 4; ++r) {
        int q = qt * 16 + quad * 4 + r;
        float val = acc[oi][qt][r] + sh;
        val = (val >= 0.f) ? val : 0.1f * val;
        z1[(((size_t)(n * 64 + q)) * 25 + v) * 128 + o] = f2bf(val);
      }
  }
}

// =============================================================================
extern "C" void kernel_launch(void* const* d_in, const int* in_sizes, int n_in,
                              void* d_out, int out_size, void* d_ws, size_t ws_size,
                              hipStream_t stream)
{
  const float* x       = (const float*)d_in[0];
  const float* w_qk_s  = (const float*)d_in[1];
  const float* b_qk_s  = (const float*)d_in[2];
  const float* alphas  = (const float*)d_in[3];
  const float* att0s   = (const float*)d_in[4];
  const float* w_outs  = (const float*)d_in[5];
  const float* b_outs  = (const float*)d_in[6];
  const float* bn_outs = (const float*)d_in[7];
  const float* w_ffs   = (const float*)d_in[8];
  const float* b_ffs   = (const float*)d_in[9];
  const float* bn_ffs  = (const float*)d_in[10];
  const float* w_ds1   = (const float*)d_in[11];
  const float* b_ds1   = (const float*)d_in[12];
  const float* bn_ds1  = (const float*)d_in[13];
  const float* w_ds2   = (const float*)d_in[14];
  const float* b_ds2   = (const float*)d_in[15];
  const float* bn_ds2  = (const float*)d_in[16];
  const float* w_qk_t  = (const float*)d_in[17];
  const float* b_qk_t  = (const float*)d_in[18];
  const float* alphat  = (const float*)d_in[19];
  const float* att0t   = (const float*)d_in[20];
  const float* w_outt  = (const float*)d_in[21];
  const float* b_outt  = (const float*)d_in[22];
  const float* bn_outt = (const float*)d_in[23];
  const float* w_fft   = (const float*)d_in[24];
  const float* b_fft   = (const float*)d_in[25];
  const float* bn_fft  = (const float*)d_in[26];
  const float* w_dt1   = (const float*)d_in[27];
  const float* b_dt1   = (const float*)d_in[28];
  const float* bn_dt1  = (const float*)d_in[29];
  const float* w_dt2   = (const float*)d_in[30];
  const float* b_dt2   = (const float*)d_in[31];
  const float* bn_dt2  = (const float*)d_in[32];

  char* ws = (char*)d_ws;
  unsigned short* WQS   = (unsigned short*)(ws + OFF_WQS);
  unsigned short* WQT   = (unsigned short*)(ws + OFF_WQT);
  unsigned short* WOUTS = (unsigned short*)(ws + OFF_WOUTS);
  unsigned short* WDS1  = (unsigned short*)(ws + OFF_WDS1);
  unsigned short* WFFS  = (unsigned short*)(ws + OFF_WFFS);
  unsigned short* WDS2  = (unsigned short*)(ws + OFF_WDS2);
  unsigned short* WOUTT = (unsigned short*)(ws + OFF_WOUTT);
  unsigned short* WDT1  = (unsigned short*)(ws + OFF_WDT1);
  unsigned short* WFFT  = (unsigned short*)(ws + OFF_WFFT);
  unsigned short* WDT2  = (unsigned short*)(ws + OFF_WDT2);
  unsigned short* WOV   = (unsigned short*)(ws + OFF_WOV);
  unsigned short* WOT   = (unsigned short*)(ws + OFF_WOT);
  float* SHA = (float*)(ws + OFF_SHA);
  float* SHB = (float*)(ws + OFF_SHB);
  float* SHC = (float*)(ws + OFF_SHC);
  float* SHD = (float*)(ws + OFF_SHD);
  unsigned short* OV    = (unsigned short*)(ws + OFF_OV);
  unsigned short* OT    = (unsigned short*)(ws + OFF_OT);
  unsigned short* ATTST = (unsigned short*)(ws + OFF_ATTST);
  unsigned short* ATTTT = (unsigned short*)(ws + OFF_ATTTT);
  unsigned short* XCL   = (unsigned short*)(ws + OFF_XCL);
  unsigned short* YCL   = (unsigned short*)(ws + OFF_YCL);
  unsigned short* RB    = (unsigned short*)(ws + OFF_RB);
  unsigned short* RA    = (unsigned short*)(ws + OFF_RA);

  k_prep<<<1650, 256, 0, stream>>>(
      w_qk_s, b_qk_s, w_outs, b_outs, bn_outs, w_ffs, b_ffs, bn_ffs,
      w_ds1, b_ds1, bn_ds1, w_ds2, b_ds2, bn_ds2, w_qk_t, b_qk_t,
      w_outt, b_outt, bn_outt, w_fft, b_fft, bn_fft,
      w_dt1, b_dt1, bn_dt1, w_dt2, b_dt2, bn_dt2, ws);

  k_convert<<<N_ * T_, 256, 0, stream>>>(x, XCL);

  // qk_s: RA[pos][192] = XCL.WQS^T + onehot(v).WOV^T   (pure GEMM, shift folded)
  k_conv<64, 64, 192, 192, 0, 0, 0, 1><<<dim3(P_ / 256, 1), 256, 0, stream>>>(
      XCL, OV, WQS, WOV, nullptr, RA);

  k_att_s<<<N_ * S_, 256, 0, stream>>>(RA, alphas, att0s, ATTST);
  // ys -> RA (qk_s dead)
  k_einsum_s<<<N_ * T_, 64, 0, stream>>>(XCL, ATTST, RA);

  // y1 = lrelu(outs(ys) + ds1(x)) -> RB
  k_conv<192, 64, 128, 128, 1, 1, 0, 0><<<dim3(P_ / 256, 1), 256, 0, stream>>>(
      RA, XCL, WOUTS, WDS1, SHA, RB);

  // y = lrelu(ffs(y1) + ds2(x)) -> YCL
  k_conv<128, 64, 128, 128, 1, 1, 0, 0><<<dim3(P_ / 256, 1), 256, 0, stream>>>(
      RB, XCL, WFFS, WDS2, SHB, YCL);

  // qk_t: RA[pos][192] = YCL.WQT^T + onehot(t).WOT^T  (two o-halves)
  k_conv<128, 64, 96, 192, 0, 0, 0, 1><<<dim3(P_ / 256, 2), 256, 0, stream>>>(
      YCL, OT, WQT, WOT, nullptr, RA);

  k_att_t<<<N_ * S_, 256, 0, stream>>>(RA, alphat, att0t, ATTTT);

  // z1 = lrelu(outt(einsum_t(y,att)) + dt1(y)) -> RB (y1 dead)
  k_fused<<<N_ * V_, 256, 0, stream>>>(YCL, ATTTT, WOUTT, WDT1, SHC, RB);

  // out = lrelu(fft(z1) + dt2(y)), fp32 NCTV
  k_conv<128, 128, 128, 128, 1, 1, 2, 0><<<dim3(P_ / 256, 1), 256, 0, stream>>>(
      RB, YCL, WFFT, WDT2, SHD, d_out);
}